// Round 13
// baseline (92.084 us; speedup 1.0000x reference)
//
#include <hip/hip_runtime.h>
#include <math.h>

#define NNODES 20000
#define NEDGES 320000
#define CDIM   256
#define NC     200
#define NB     4096                 // nearest-neighbor bins; rows alloc'd 4160 (130*32)
#define TROWS  4160
#define DRANGE 24.0f
#define DELTA  (DRANGE / (float)NB)
#define INVDEL ((float)NB / DRANGE)
#define NTHR   256
#define RS     264                  // LDS row stride in ushorts (528B)
#define CAP    48                   // bucket capacity per node (Poisson(16); P(deg>=48)~1e-11)
#define GNR    16                   // rows per fused gather+node tile

#define PACKB  1248
#define ZEROB  20
#define FILLB  (NEDGES / NTHR)                // 1250 (1 edge/thread, FIRST in grid)
#define XW3B2  (NNODES / 16)                  // 1250 (16-row xw3 tiles)
#define TBLK2  (TROWS / 32)                   // 130
#define GNB    (NNODES / GNR)                 // 1250

typedef __attribute__((ext_vector_type(8))) short bf16x8;
typedef __attribute__((ext_vector_type(4))) float f32x4;
typedef __attribute__((ext_vector_type(8))) unsigned short u16x8;

__device__ __forceinline__ unsigned short f2bf(float f) {
    unsigned int u = __float_as_uint(f);
    unsigned int r = (u + 0x7FFFu + ((u >> 16) & 1u)) >> 16;   // RNE
    return (unsigned short)r;
}
__device__ __forceinline__ float bf2f(unsigned short h) {
    return __uint_as_float(((unsigned int)h) << 16);
}
__device__ __forceinline__ float ssp_f(float x) {
    const float LOG2V = 0.6931471805599453f;
    if (x < 14.0f) return __logf(1.0f + __expf(x)) - LOG2V;
    return x - LOG2V;
}

// ---------- pack weights + zero cnt (one small kernel) ----------
__global__ __launch_bounds__(NTHR)
void packzero_kernel(const float* __restrict__ w3, const float* __restrict__ w4,
                     const float* __restrict__ w5, const float* __restrict__ w1,
                     const float* __restrict__ w2,
                     unsigned short* __restrict__ w3p, unsigned short* __restrict__ w4p,
                     unsigned short* __restrict__ w5p, unsigned short* __restrict__ w1p,
                     unsigned short* __restrict__ w2p,
                     int4* __restrict__ cnt4)
{
    if (blockIdx.x < PACKB) {
        int idx = blockIdx.x * NTHR + threadIdx.x;             // 0 .. 319487
        if (idx < 196608) {
            int m = idx >> 16;
            int r = idx & 65535;
            int j = r & 7, c = (r >> 3) & 255, lg = (r >> 11) & 3, kt = r >> 13;
            int k = kt * 32 + lg * 8 + j;
            const float* w = (m == 0) ? w3 : (m == 1) ? w4 : w5;
            unsigned short* wp = (m == 0) ? w3p : (m == 1) ? w4p : w5p;
            wp[r] = f2bf(w[k * CDIM + c]);
        } else if (idx < 253952) {
            int r = idx - 196608;                        // w1p: 224*256 = 57344
            int j = r & 7, c = (r >> 3) & 255, lg = (r >> 11) & 3, kt = r >> 13;
            int k = kt * 32 + lg * 8 + j;
            w1p[r] = (k < NC) ? f2bf(w1[k * CDIM + c]) : (unsigned short)0;
        } else {
            int r = idx - 253952;                        // w2p: 65536
            int j = r & 7, c = (r >> 3) & 255, lg = (r >> 11) & 3, kt = r >> 13;
            int k = kt * 32 + lg * 8 + j;
            w2p[r] = f2bf(w2[k * CDIM + c]);
        }
    } else {
        int i = (blockIdx.x - PACKB) * NTHR + threadIdx.x;
        if (i < NNODES / 4) cnt4[i] = make_int4(0, 0, 0, 0);
    }
}

// ---------- mega kernel: fill (1 edge/thread, FIRST) + xw3 (16-row) + table ----------
// fill first so its atomic/scatter latency overlaps the MFMA blocks behind it.
// Slot packed to 4B: (idx << 15) | sender  (sender < 2^15, idx < 2^12).
// Table NON-interleaved [TROWS][256]; gather does nearest-neighbor lookup.
__global__ __launch_bounds__(NTHR, 4)
void mega_kernel(const unsigned short* __restrict__ w1p, const float* __restrict__ b1,
                 const unsigned short* __restrict__ w2p, const float* __restrict__ b2,
                 unsigned short* __restrict__ Wtb,
                 const float* __restrict__ x,
                 const unsigned short* __restrict__ w3p,
                 unsigned short* __restrict__ xw3h,
                 const float* __restrict__ pos,
                 const int* __restrict__ snd,
                 const int* __restrict__ rcv,
                 int* __restrict__ cnt,
                 int* __restrict__ slots)
{
    __shared__ unsigned short s_a[32 * RS];      // 16896 B (table uses 32 rows)
    const int t = threadIdx.x;

    if (blockIdx.x < FILLB) {
        // ----- fill: edge bucketing, 1 edge per thread (1250 blocks) -----
        int e = blockIdx.x * NTHR + t;
        int s = snd[e], r = rcv[e];
        float dx = pos[r * 3 + 0] - pos[s * 3 + 0];
        float dy = pos[r * 3 + 1] - pos[s * 3 + 1];
        float dz = pos[r * 3 + 2] - pos[s * 3 + 2];
        float d = sqrtf(dx * dx + dy * dy + dz * dz);
        float u = fminf(d * INVDEL, (float)NB - 1.0f);
        int idx = (int)(u + 0.5f);
        if (idx > NB - 1) idx = NB - 1;
        int rank = atomicAdd(&cnt[r], 1);
        if (rank < CAP) {
            slots[(size_t)r * CAP + rank] = (idx << 15) | s;
        }
    } else if (blockIdx.x < FILLB + XW3B2) {
        // ----- xw3 = x @ w3, 16 rows per block (1250 blocks) -----
        const int m0 = (blockIdx.x - FILLB) * 16;

        {
            int row = t >> 4, c0 = (t & 15) * 16;
            const float* src = &x[(size_t)(m0 + row) * CDIM + c0];
            unsigned short* dst = &s_a[row * RS + c0];
            #pragma unroll
            for (int oc = 0; oc < 2; ++oc) {
                float4 a = *(const float4*)&src[oc * 8];
                float4 b = *(const float4*)&src[oc * 8 + 4];
                u16x8 v;
                v[0] = f2bf(a.x); v[1] = f2bf(a.y); v[2] = f2bf(a.z); v[3] = f2bf(a.w);
                v[4] = f2bf(b.x); v[5] = f2bf(b.y); v[6] = f2bf(b.z); v[7] = f2bf(b.w);
                *(u16x8*)&dst[oc * 8] = v;
            }
        }
        __syncthreads();

        const int l = t & 63, w = t >> 6, lr = l & 15, lg = l >> 4, nb = w * 64;
        f32x4 acc2[4];
        #pragma unroll
        for (int nt = 0; nt < 4; ++nt) acc2[nt] = (f32x4)0.0f;

        #pragma unroll 2
        for (int kt = 0; kt < 8; ++kt) {
            bf16x8 a = *(const bf16x8*)&s_a[lr * RS + kt * 32 + lg * 8];
            #pragma unroll
            for (int nt = 0; nt < 4; ++nt) {
                bf16x8 b = *(const bf16x8*)&w3p[(size_t)(((kt * 4 + lg) * 256) + nb + nt * 16 + lr) * 8];
                acc2[nt] = __builtin_amdgcn_mfma_f32_16x16x32_bf16(a, b, acc2[nt], 0, 0, 0);
            }
        }

        #pragma unroll
        for (int nt = 0; nt < 4; ++nt) {
            int col = nb + nt * 16 + lr;
            #pragma unroll
            for (int rr = 0; rr < 4; ++rr) {
                int row = m0 + lg * 4 + rr;
                xw3h[(size_t)row * CDIM + col] = f2bf(acc2[nt][rr]);
            }
        }
    } else {
        // ----- filter table, 32 bins per block (130 blocks) -----
        const int m0 = (blockIdx.x - FILLB - XW3B2) * 32;
        const float cstep = 20.0f / 199.0f;

        {
            int row = t >> 3;
            int k0 = (t & 7) * 28;
            float d = (float)(m0 + row) * DELTA;
            #pragma unroll
            for (int j = 0; j < 28; ++j) {
                int k = k0 + j;
                float dd = d - (float)k * cstep;
                float v = (k < NC) ? __expf(-10.0f * dd * dd) : 0.0f;
                s_a[row * RS + k] = f2bf(v);
            }
        }
        __syncthreads();

        const int l = t & 63, w = t >> 6, lr = l & 15, lg = l >> 4, nb = w * 64;
        f32x4 acc[2][4];
        #pragma unroll
        for (int mt = 0; mt < 2; ++mt)
            #pragma unroll
            for (int nt = 0; nt < 4; ++nt) acc[mt][nt] = (f32x4)0.0f;

        // GEMM1: K = 224
        #pragma unroll 2
        for (int kt = 0; kt < 7; ++kt) {
            bf16x8 a[2];
            #pragma unroll
            for (int mt = 0; mt < 2; ++mt)
                a[mt] = *(const bf16x8*)&s_a[(mt * 16 + lr) * RS + kt * 32 + lg * 8];
            #pragma unroll
            for (int nt = 0; nt < 4; ++nt) {
                bf16x8 b = *(const bf16x8*)&w1p[(size_t)(((kt * 4 + lg) * 256) + nb + nt * 16 + lr) * 8];
                #pragma unroll
                for (int mt = 0; mt < 2; ++mt)
                    acc[mt][nt] = __builtin_amdgcn_mfma_f32_16x16x32_bf16(a[mt], b, acc[mt][nt], 0, 0, 0);
            }
        }
        __syncthreads();

        #pragma unroll
        for (int nt = 0; nt < 4; ++nt) {
            int col = nb + nt * 16 + lr;
            float bias = b1[col];
            #pragma unroll
            for (int mt = 0; mt < 2; ++mt)
                #pragma unroll
                for (int rr = 0; rr < 4; ++rr)
                    s_a[(mt * 16 + lg * 4 + rr) * RS + col] = f2bf(ssp_f(acc[mt][nt][rr] + bias));
        }
        __syncthreads();

        #pragma unroll
        for (int mt = 0; mt < 2; ++mt)
            #pragma unroll
            for (int nt = 0; nt < 4; ++nt) acc[mt][nt] = (f32x4)0.0f;

        // GEMM2: K = 256
        #pragma unroll 2
        for (int kt = 0; kt < 8; ++kt) {
            bf16x8 a[2];
            #pragma unroll
            for (int mt = 0; mt < 2; ++mt)
                a[mt] = *(const bf16x8*)&s_a[(mt * 16 + lr) * RS + kt * 32 + lg * 8];
            #pragma unroll
            for (int nt = 0; nt < 4; ++nt) {
                bf16x8 b = *(const bf16x8*)&w2p[(size_t)(((kt * 4 + lg) * 256) + nb + nt * 16 + lr) * 8];
                #pragma unroll
                for (int mt = 0; mt < 2; ++mt)
                    acc[mt][nt] = __builtin_amdgcn_mfma_f32_16x16x32_bf16(a[mt], b, acc[mt][nt], 0, 0, 0);
            }
        }

        #pragma unroll
        for (int nt = 0; nt < 4; ++nt) {
            int col = nb + nt * 16 + lr;
            float bias = b2[col];
            #pragma unroll
            for (int mt = 0; mt < 2; ++mt)
                #pragma unroll
                for (int rr = 0; rr < 4; ++rr) {
                    int row = m0 + mt * 16 + lg * 4 + rr;
                    Wtb[(size_t)row * CDIM + col] = f2bf(ssp_f(acc[mt][nt][rr] + bias));
                }
        }
    }
}

// ---------- fused gather + node MLP: 16 nodes per block (R12 form, UNCHANGED) ------
// Phase 1 (gather): wave w accumulates conv for rows w*4..w*4+3; per edge ONE 8B
// nearest-table load + ONE 8B feature load per lane (16 cache lines/edge).
// Slots are packed 4B ints: sender = v & 0x7FFF, table idx = v >> 15.
// Phase 2 (MLP): out = x + ssp(conv@w4+b4) @ w5 + b5 from the LDS-staged rows.
// NOTE (R1/R8/R10 lesson): keep (256,4) — cutting gather below ~40 VGPR loses.

#define GDESC8(src) { \
    int v0 = __shfl((src), 0), v1 = __shfl((src), 1); \
    int v2 = __shfl((src), 2), v3 = __shfl((src), 3); \
    int v4 = __shfl((src), 4), v5 = __shfl((src), 5); \
    int v6 = __shfl((src), 6), v7 = __shfl((src), 7); \
    sD0 = v0 & 32767; iD0 = v0 >> 15; \
    sD1 = v1 & 32767; iD1 = v1 >> 15; \
    sD2 = v2 & 32767; iD2 = v2 >> 15; \
    sD3 = v3 & 32767; iD3 = v3 >> 15; \
    sD4 = v4 & 32767; iD4 = v4 >> 15; \
    sD5 = v5 & 32767; iD5 = v5 >> 15; \
    sD6 = v6 & 32767; iD6 = v6 >> 15; \
    sD7 = v7 & 32767; iD7 = v7 >> 15; }

#define GDESC4(src) { \
    int v0 = __shfl((src), 0), v1 = __shfl((src), 1); \
    int v2 = __shfl((src), 2), v3 = __shfl((src), 3); \
    sD0 = v0 & 32767; iD0 = v0 >> 15; \
    sD1 = v1 & 32767; iD1 = v1 >> 15; \
    sD2 = v2 & 32767; iD2 = v2 >> 15; \
    sD3 = v3 & 32767; iD3 = v3 >> 15; }

#define GLOAD1(e) \
    ushort4 wa##e = *(const ushort4*)&Wtb[(size_t)iD##e * CDIM + c4]; \
    ushort4 fx##e = *(const ushort4*)&xw3h[(size_t)sD##e * CDIM + c4];

#define GFMA1(e) { \
    acc.x = fmaf(bf2f(wa##e.x), bf2f(fx##e.x), acc.x); \
    acc.y = fmaf(bf2f(wa##e.y), bf2f(fx##e.y), acc.y); \
    acc.z = fmaf(bf2f(wa##e.z), bf2f(fx##e.z), acc.z); \
    acc.w = fmaf(bf2f(wa##e.w), bf2f(fx##e.w), acc.w); }

__global__ __launch_bounds__(NTHR, 4)
void gathernode_kernel(const int* __restrict__ cnt,
                       const int* __restrict__ slots,
                       const unsigned short* __restrict__ Wtb,
                       const unsigned short* __restrict__ xw3h,
                       const unsigned short* __restrict__ w4p, const float* __restrict__ b4,
                       const unsigned short* __restrict__ w5p, const float* __restrict__ b5,
                       const float* __restrict__ x,
                       float* __restrict__ out)
{
    __shared__ unsigned short s_a[GNR * RS];     // 8448 B
    const int t = threadIdx.x;
    const int w = t >> 6, l = t & 63;
    const int c4 = l * 4;          // channel offset (ushorts) in Wtb / xw3h / s_a rows
    const int m0 = blockIdx.x * GNR;             // NNODES % 16 == 0 -> no guards

    // ---- phase 1: gather 4 nodes per wave ----
    for (int rr = 0; rr < 4; ++rr) {
        const int row = w * 4 + rr;
        const int n = m0 + row;
        const int* sl = slots + (size_t)n * CAP;
        int deg = cnt[n];
        deg = deg > CAP ? CAP : deg;

        float4 acc = make_float4(0.0f, 0.0f, 0.0f, 0.0f);
        int sD0, sD1, sD2, sD3, sD4, sD5, sD6, sD7;
        int iD0, iD1, iD2, iD3, iD4, iD5, iD6, iD7;

        int j = 0;
        int dscN = 0;
        if (deg >= 8) dscN = sl[l & 7];

        while (j + 8 <= deg) {
            GDESC8(dscN)
            if (j + 16 <= deg) dscN = sl[j + 8 + (l & 7)];   // next batch descriptors
            GLOAD1(0) GLOAD1(1) GLOAD1(2) GLOAD1(3)
            GLOAD1(4) GLOAD1(5) GLOAD1(6) GLOAD1(7)
            GFMA1(0) GFMA1(1) GFMA1(2) GFMA1(3)
            GFMA1(4) GFMA1(5) GFMA1(6) GFMA1(7)
            j += 8;
        }

        if (j + 4 <= deg) {
            int d4 = sl[j + (l & 3)];
            GDESC4(d4)
            GLOAD1(0) GLOAD1(1) GLOAD1(2) GLOAD1(3)
            GFMA1(0) GFMA1(1) GFMA1(2) GFMA1(3)
            j += 4;
        }

        // serial tail (<= 3 edges): loads first, then FMAs
        {
            int rem = deg - j;
            if (rem > 0) {
                int sv0 = sl[j];
                sD0 = sv0 & 32767; iD0 = sv0 >> 15;
                GLOAD1(0)
                if (rem > 1) {
                    int sv1 = sl[j + 1];
                    sD1 = sv1 & 32767; iD1 = sv1 >> 15;
                    GLOAD1(1)
                    if (rem > 2) {
                        int sv2 = sl[j + 2];
                        sD2 = sv2 & 32767; iD2 = sv2 >> 15;
                        GLOAD1(2)
                        GFMA1(2)
                    }
                    GFMA1(1)
                }
                GFMA1(0)
            }
        }

        ushort4 st;
        st.x = f2bf(acc.x); st.y = f2bf(acc.y); st.z = f2bf(acc.z); st.w = f2bf(acc.w);
        *(ushort4*)&s_a[row * RS + c4] = st;
    }
    __syncthreads();

    // ---- phase 2: node MLP on the 16 staged rows ----
    const int lr = l & 15, lg = l >> 4, nb = w * 64;
    f32x4 acc2[4];
    #pragma unroll
    for (int nt = 0; nt < 4; ++nt) acc2[nt] = (f32x4)0.0f;

    #pragma unroll 2
    for (int kt = 0; kt < 8; ++kt) {
        bf16x8 a = *(const bf16x8*)&s_a[lr * RS + kt * 32 + lg * 8];
        #pragma unroll
        for (int nt = 0; nt < 4; ++nt) {
            bf16x8 b = *(const bf16x8*)&w4p[(size_t)(((kt * 4 + lg) * 256) + nb + nt * 16 + lr) * 8];
            acc2[nt] = __builtin_amdgcn_mfma_f32_16x16x32_bf16(a, b, acc2[nt], 0, 0, 0);
        }
    }
    __syncthreads();

    #pragma unroll
    for (int nt = 0; nt < 4; ++nt) {
        int col = nb + nt * 16 + lr;
        float bias = b4[col];
        #pragma unroll
        for (int rr = 0; rr < 4; ++rr)
            s_a[(lg * 4 + rr) * RS + col] = f2bf(ssp_f(acc2[nt][rr] + bias));
    }
    __syncthreads();

    #pragma unroll
    for (int nt = 0; nt < 4; ++nt) acc2[nt] = (f32x4)0.0f;

    #pragma unroll 2
    for (int kt = 0; kt < 8; ++kt) {
        bf16x8 a = *(const bf16x8*)&s_a[lr * RS + kt * 32 + lg * 8];
        #pragma unroll
        for (int nt = 0; nt < 4; ++nt) {
            bf16x8 b = *(const bf16x8*)&w5p[(size_t)(((kt * 4 + lg) * 256) + nb + nt * 16 + lr) * 8];
            acc2[nt] = __builtin_amdgcn_mfma_f32_16x16x32_bf16(a, b, acc2[nt], 0, 0, 0);
        }
    }

    #pragma unroll
    for (int nt = 0; nt < 4; ++nt) {
        int col = nb + nt * 16 + lr;
        float bias = b5[col];
        #pragma unroll
        for (int rr = 0; rr < 4; ++rr) {
            int row = m0 + lg * 4 + rr;
            out[(size_t)row * CDIM + col] =
                acc2[nt][rr] + bias + x[(size_t)row * CDIM + col];
        }
    }
}

extern "C" void kernel_launch(void* const* d_in, const int* in_sizes, int n_in,
                              void* d_out, int out_size, void* d_ws, size_t ws_size,
                              hipStream_t stream) {
    const float* pos = (const float*)d_in[0];
    const float* x   = (const float*)d_in[1];
    const int*   snd = (const int*)d_in[2];
    const int*   rcv = (const int*)d_in[3];
    const float* w1  = (const float*)d_in[4];
    const float* b1  = (const float*)d_in[5];
    const float* w2  = (const float*)d_in[6];
    const float* b2  = (const float*)d_in[7];
    const float* w3  = (const float*)d_in[8];
    const float* w4  = (const float*)d_in[9];
    const float* b4  = (const float*)d_in[10];
    const float* w5  = (const float*)d_in[11];
    const float* b5  = (const float*)d_in[12];

    float* out  = (float*)d_out;

    // ws: xw3h bf16 | Wtb bf16 4160x256 | w3p/w4p/w5p | w1p | w2p | cnt | slots(int)
    unsigned char* ws = (unsigned char*)d_ws;
    unsigned short* xw3h = (unsigned short*)ws;
    size_t off = (size_t)NNODES * CDIM * 2;
    unsigned short* Wtb = (unsigned short*)(ws + off); off += (size_t)TROWS * CDIM * 2;
    unsigned short* w3p = (unsigned short*)(ws + off); off += 65536 * 2;
    unsigned short* w4p = (unsigned short*)(ws + off); off += 65536 * 2;
    unsigned short* w5p = (unsigned short*)(ws + off); off += 65536 * 2;
    unsigned short* w1p = (unsigned short*)(ws + off); off += 57344 * 2;
    unsigned short* w2p = (unsigned short*)(ws + off); off += 65536 * 2;
    int* cnt = (int*)(ws + off);                       off += (size_t)NNODES * 4;
    int* slots = (int*)(ws + off);

    packzero_kernel<<<PACKB + ZEROB, NTHR, 0, stream>>>(w3, w4, w5, w1, w2,
                                                        w3p, w4p, w5p, w1p, w2p,
                                                        (int4*)cnt);
    mega_kernel<<<FILLB + XW3B2 + TBLK2, NTHR, 0, stream>>>(w1p, b1, w2p, b2, Wtb,
                                                            x, w3p, xw3h,
                                                            pos, snd, rcv, cnt, slots);
    gathernode_kernel<<<GNB, NTHR, 0, stream>>>(cnt, slots, Wtb, xw3h,
                                                w4p, b4, w5p, b5, x, out);
}

// Round 14
// 83.612 us; speedup vs baseline: 1.1013x; 1.1013x over previous
//
#include <hip/hip_runtime.h>
#include <math.h>

#define NNODES 20000
#define NEDGES 320000
#define CDIM   256
#define NC     200
#define NB     4096                 // nearest-neighbor bins; rows alloc'd 4160 (130*32)
#define TROWS  4160
#define DRANGE 24.0f
#define DELTA  (DRANGE / (float)NB)
#define INVDEL ((float)NB / DRANGE)
#define NTHR   256
#define RS     264                  // LDS row stride in ushorts (528B)
#define CAP    48                   // bucket capacity per node (Poisson(16); P(deg>=48)~1e-11)
#define GNR    16                   // rows per fused gather+node tile

#define PACKB  1248
#define ZEROB  20
#define TBLK2  (TROWS / 32)                   // 130
#define XW3B2  (NNODES / 16)                  // 1250 (16-row xw3 tiles)
#define FILLB4 ((NEDGES / 4 + NTHR - 1) / NTHR)   // 313 (4 edges/thread, LAST in grid)
#define GNB    (NNODES / GNR)                 // 1250

typedef __attribute__((ext_vector_type(8))) short bf16x8;
typedef __attribute__((ext_vector_type(4))) float f32x4;
typedef __attribute__((ext_vector_type(8))) unsigned short u16x8;

__device__ __forceinline__ unsigned short f2bf(float f) {
    unsigned int u = __float_as_uint(f);
    unsigned int r = (u + 0x7FFFu + ((u >> 16) & 1u)) >> 16;   // RNE
    return (unsigned short)r;
}
__device__ __forceinline__ float bf2f(unsigned short h) {
    return __uint_as_float(((unsigned int)h) << 16);
}
__device__ __forceinline__ float ssp_f(float x) {
    const float LOG2V = 0.6931471805599453f;
    if (x < 14.0f) return __logf(1.0f + __expf(x)) - LOG2V;
    return x - LOG2V;
}

// ---------- pack weights + zero cnt (one small kernel) ----------
__global__ __launch_bounds__(NTHR)
void packzero_kernel(const float* __restrict__ w3, const float* __restrict__ w4,
                     const float* __restrict__ w5, const float* __restrict__ w1,
                     const float* __restrict__ w2,
                     unsigned short* __restrict__ w3p, unsigned short* __restrict__ w4p,
                     unsigned short* __restrict__ w5p, unsigned short* __restrict__ w1p,
                     unsigned short* __restrict__ w2p,
                     int4* __restrict__ cnt4)
{
    if (blockIdx.x < PACKB) {
        int idx = blockIdx.x * NTHR + threadIdx.x;             // 0 .. 319487
        if (idx < 196608) {
            int m = idx >> 16;
            int r = idx & 65535;
            int j = r & 7, c = (r >> 3) & 255, lg = (r >> 11) & 3, kt = r >> 13;
            int k = kt * 32 + lg * 8 + j;
            const float* w = (m == 0) ? w3 : (m == 1) ? w4 : w5;
            unsigned short* wp = (m == 0) ? w3p : (m == 1) ? w4p : w5p;
            wp[r] = f2bf(w[k * CDIM + c]);
        } else if (idx < 253952) {
            int r = idx - 196608;                        // w1p: 224*256 = 57344
            int j = r & 7, c = (r >> 3) & 255, lg = (r >> 11) & 3, kt = r >> 13;
            int k = kt * 32 + lg * 8 + j;
            w1p[r] = (k < NC) ? f2bf(w1[k * CDIM + c]) : (unsigned short)0;
        } else {
            int r = idx - 253952;                        // w2p: 65536
            int j = r & 7, c = (r >> 3) & 255, lg = (r >> 11) & 3, kt = r >> 13;
            int k = kt * 32 + lg * 8 + j;
            w2p[r] = f2bf(w2[k * CDIM + c]);
        }
    } else {
        int i = (blockIdx.x - PACKB) * NTHR + threadIdx.x;
        if (i < NNODES / 4) cnt4[i] = make_int4(0, 0, 0, 0);
    }
}

// ---------- mega kernel: table (32-bin, 130) + xw3 (16-row, 1250) + fill (313, LAST)
// R12-proven ordering: MFMA blocks first so fill's atomic/scatter latency overlaps
// them as CUs free up (R13 showed fill-FIRST serializes and costs ~8 us).
// Slot packed to 4B: (idx << 15) | sender  (sender < 2^15, idx < 2^12).
// Table NON-interleaved [TROWS][256]; gather does nearest-neighbor lookup.
__global__ __launch_bounds__(NTHR, 4)
void mega_kernel(const unsigned short* __restrict__ w1p, const float* __restrict__ b1,
                 const unsigned short* __restrict__ w2p, const float* __restrict__ b2,
                 unsigned short* __restrict__ Wtb,
                 const float* __restrict__ x,
                 const unsigned short* __restrict__ w3p,
                 unsigned short* __restrict__ xw3h,
                 const float* __restrict__ pos,
                 const int* __restrict__ snd,
                 const int* __restrict__ rcv,
                 int* __restrict__ cnt,
                 int* __restrict__ slots)
{
    __shared__ unsigned short s_a[32 * RS];      // 16896 B (table uses 32 rows)
    const int t = threadIdx.x;

    if (blockIdx.x < TBLK2) {
        // ----- filter table, 32 bins per block -----
        const int m0 = blockIdx.x * 32;
        const float cstep = 20.0f / 199.0f;

        {
            int row = t >> 3;
            int k0 = (t & 7) * 28;
            float d = (float)(m0 + row) * DELTA;
            #pragma unroll
            for (int j = 0; j < 28; ++j) {
                int k = k0 + j;
                float dd = d - (float)k * cstep;
                float v = (k < NC) ? __expf(-10.0f * dd * dd) : 0.0f;
                s_a[row * RS + k] = f2bf(v);
            }
        }
        __syncthreads();

        const int l = t & 63, w = t >> 6, lr = l & 15, lg = l >> 4, nb = w * 64;
        f32x4 acc[2][4];
        #pragma unroll
        for (int mt = 0; mt < 2; ++mt)
            #pragma unroll
            for (int nt = 0; nt < 4; ++nt) acc[mt][nt] = (f32x4)0.0f;

        // GEMM1: K = 224
        #pragma unroll 2
        for (int kt = 0; kt < 7; ++kt) {
            bf16x8 a[2];
            #pragma unroll
            for (int mt = 0; mt < 2; ++mt)
                a[mt] = *(const bf16x8*)&s_a[(mt * 16 + lr) * RS + kt * 32 + lg * 8];
            #pragma unroll
            for (int nt = 0; nt < 4; ++nt) {
                bf16x8 b = *(const bf16x8*)&w1p[(size_t)(((kt * 4 + lg) * 256) + nb + nt * 16 + lr) * 8];
                #pragma unroll
                for (int mt = 0; mt < 2; ++mt)
                    acc[mt][nt] = __builtin_amdgcn_mfma_f32_16x16x32_bf16(a[mt], b, acc[mt][nt], 0, 0, 0);
            }
        }
        __syncthreads();

        #pragma unroll
        for (int nt = 0; nt < 4; ++nt) {
            int col = nb + nt * 16 + lr;
            float bias = b1[col];
            #pragma unroll
            for (int mt = 0; mt < 2; ++mt)
                #pragma unroll
                for (int rr = 0; rr < 4; ++rr)
                    s_a[(mt * 16 + lg * 4 + rr) * RS + col] = f2bf(ssp_f(acc[mt][nt][rr] + bias));
        }
        __syncthreads();

        #pragma unroll
        for (int mt = 0; mt < 2; ++mt)
            #pragma unroll
            for (int nt = 0; nt < 4; ++nt) acc[mt][nt] = (f32x4)0.0f;

        // GEMM2: K = 256
        #pragma unroll 2
        for (int kt = 0; kt < 8; ++kt) {
            bf16x8 a[2];
            #pragma unroll
            for (int mt = 0; mt < 2; ++mt)
                a[mt] = *(const bf16x8*)&s_a[(mt * 16 + lr) * RS + kt * 32 + lg * 8];
            #pragma unroll
            for (int nt = 0; nt < 4; ++nt) {
                bf16x8 b = *(const bf16x8*)&w2p[(size_t)(((kt * 4 + lg) * 256) + nb + nt * 16 + lr) * 8];
                #pragma unroll
                for (int mt = 0; mt < 2; ++mt)
                    acc[mt][nt] = __builtin_amdgcn_mfma_f32_16x16x32_bf16(a[mt], b, acc[mt][nt], 0, 0, 0);
            }
        }

        #pragma unroll
        for (int nt = 0; nt < 4; ++nt) {
            int col = nb + nt * 16 + lr;
            float bias = b2[col];
            #pragma unroll
            for (int mt = 0; mt < 2; ++mt)
                #pragma unroll
                for (int rr = 0; rr < 4; ++rr) {
                    int row = m0 + mt * 16 + lg * 4 + rr;
                    Wtb[(size_t)row * CDIM + col] = f2bf(ssp_f(acc[mt][nt][rr] + bias));
                }
        }
    } else if (blockIdx.x < TBLK2 + XW3B2) {
        // ----- xw3 = x @ w3, 16 rows per block (1250 blocks) -----
        const int m0 = (blockIdx.x - TBLK2) * 16;

        {
            int row = t >> 4, c0 = (t & 15) * 16;
            const float* src = &x[(size_t)(m0 + row) * CDIM + c0];
            unsigned short* dst = &s_a[row * RS + c0];
            #pragma unroll
            for (int oc = 0; oc < 2; ++oc) {
                float4 a = *(const float4*)&src[oc * 8];
                float4 b = *(const float4*)&src[oc * 8 + 4];
                u16x8 v;
                v[0] = f2bf(a.x); v[1] = f2bf(a.y); v[2] = f2bf(a.z); v[3] = f2bf(a.w);
                v[4] = f2bf(b.x); v[5] = f2bf(b.y); v[6] = f2bf(b.z); v[7] = f2bf(b.w);
                *(u16x8*)&dst[oc * 8] = v;
            }
        }
        __syncthreads();

        const int l = t & 63, w = t >> 6, lr = l & 15, lg = l >> 4, nb = w * 64;
        f32x4 acc2[4];
        #pragma unroll
        for (int nt = 0; nt < 4; ++nt) acc2[nt] = (f32x4)0.0f;

        #pragma unroll 2
        for (int kt = 0; kt < 8; ++kt) {
            bf16x8 a = *(const bf16x8*)&s_a[lr * RS + kt * 32 + lg * 8];
            #pragma unroll
            for (int nt = 0; nt < 4; ++nt) {
                bf16x8 b = *(const bf16x8*)&w3p[(size_t)(((kt * 4 + lg) * 256) + nb + nt * 16 + lr) * 8];
                acc2[nt] = __builtin_amdgcn_mfma_f32_16x16x32_bf16(a, b, acc2[nt], 0, 0, 0);
            }
        }

        #pragma unroll
        for (int nt = 0; nt < 4; ++nt) {
            int col = nb + nt * 16 + lr;
            #pragma unroll
            for (int rr = 0; rr < 4; ++rr) {
                int row = m0 + lg * 4 + rr;
                xw3h[(size_t)row * CDIM + col] = f2bf(acc2[nt][rr]);
            }
        }
    } else {
        // ----- fill: edge bucketing, 4 edges per thread (313 blocks, LAST) -----
        int g = (blockIdx.x - TBLK2 - XW3B2) * NTHR + threadIdx.x;   // int4 index
        if (g >= NEDGES / 4) return;
        int4 s4 = *(const int4*)&snd[g * 4];
        int4 r4 = *(const int4*)&rcv[g * 4];
        int ss[4] = { s4.x, s4.y, s4.z, s4.w };
        int rr_[4] = { r4.x, r4.y, r4.z, r4.w };
        float psx[4], psy[4], psz[4], prx[4], pry[4], prz[4];
        #pragma unroll
        for (int q = 0; q < 4; ++q) {
            psx[q] = pos[ss[q] * 3 + 0]; psy[q] = pos[ss[q] * 3 + 1]; psz[q] = pos[ss[q] * 3 + 2];
            prx[q] = pos[rr_[q] * 3 + 0]; pry[q] = pos[rr_[q] * 3 + 1]; prz[q] = pos[rr_[q] * 3 + 2];
        }
        #pragma unroll
        for (int q = 0; q < 4; ++q) {
            float dx = prx[q] - psx[q];
            float dy = pry[q] - psy[q];
            float dz = prz[q] - psz[q];
            float d = sqrtf(dx * dx + dy * dy + dz * dz);
            float u = fminf(d * INVDEL, (float)NB - 1.0f);
            int idx = (int)(u + 0.5f);
            if (idx > NB - 1) idx = NB - 1;
            int rank = atomicAdd(&cnt[rr_[q]], 1);
            if (rank < CAP) {
                slots[(size_t)rr_[q] * CAP + rank] = (idx << 15) | ss[q];
            }
        }
    }
}

// ---------- fused gather + node MLP: 16 nodes per block (R12 form) ----------
// Phase 1 (gather): wave w accumulates conv for rows w*4..w*4+3; per edge ONE 8B
// nearest-table load + ONE 8B feature load per lane (16 cache lines/edge).
// Slots are packed 4B ints: sender = v & 0x7FFF, table idx = v >> 15.
// Phase 2 (MLP): out = x + ssp(conv@w4+b4) @ w5 + b5 from the LDS-staged rows.
// NOTE (R1/R8/R10 lesson): keep (256,4) — cutting gather below ~40 VGPR loses.

#define GDESC8(src) { \
    int v0 = __shfl((src), 0), v1 = __shfl((src), 1); \
    int v2 = __shfl((src), 2), v3 = __shfl((src), 3); \
    int v4 = __shfl((src), 4), v5 = __shfl((src), 5); \
    int v6 = __shfl((src), 6), v7 = __shfl((src), 7); \
    sD0 = v0 & 32767; iD0 = v0 >> 15; \
    sD1 = v1 & 32767; iD1 = v1 >> 15; \
    sD2 = v2 & 32767; iD2 = v2 >> 15; \
    sD3 = v3 & 32767; iD3 = v3 >> 15; \
    sD4 = v4 & 32767; iD4 = v4 >> 15; \
    sD5 = v5 & 32767; iD5 = v5 >> 15; \
    sD6 = v6 & 32767; iD6 = v6 >> 15; \
    sD7 = v7 & 32767; iD7 = v7 >> 15; }

#define GDESC4(src) { \
    int v0 = __shfl((src), 0), v1 = __shfl((src), 1); \
    int v2 = __shfl((src), 2), v3 = __shfl((src), 3); \
    sD0 = v0 & 32767; iD0 = v0 >> 15; \
    sD1 = v1 & 32767; iD1 = v1 >> 15; \
    sD2 = v2 & 32767; iD2 = v2 >> 15; \
    sD3 = v3 & 32767; iD3 = v3 >> 15; }

#define GLOAD1(e) \
    ushort4 wa##e = *(const ushort4*)&Wtb[(size_t)iD##e * CDIM + c4]; \
    ushort4 fx##e = *(const ushort4*)&xw3h[(size_t)sD##e * CDIM + c4];

#define GFMA1(e) { \
    acc.x = fmaf(bf2f(wa##e.x), bf2f(fx##e.x), acc.x); \
    acc.y = fmaf(bf2f(wa##e.y), bf2f(fx##e.y), acc.y); \
    acc.z = fmaf(bf2f(wa##e.z), bf2f(fx##e.z), acc.z); \
    acc.w = fmaf(bf2f(wa##e.w), bf2f(fx##e.w), acc.w); }

__global__ __launch_bounds__(NTHR, 4)
void gathernode_kernel(const int* __restrict__ cnt,
                       const int* __restrict__ slots,
                       const unsigned short* __restrict__ Wtb,
                       const unsigned short* __restrict__ xw3h,
                       const unsigned short* __restrict__ w4p, const float* __restrict__ b4,
                       const unsigned short* __restrict__ w5p, const float* __restrict__ b5,
                       const float* __restrict__ x,
                       float* __restrict__ out)
{
    __shared__ unsigned short s_a[GNR * RS];     // 8448 B
    const int t = threadIdx.x;
    const int w = t >> 6, l = t & 63;
    const int c4 = l * 4;          // channel offset (ushorts) in Wtb / xw3h / s_a rows
    const int m0 = blockIdx.x * GNR;             // NNODES % 16 == 0 -> no guards

    // ---- phase 1: gather 4 nodes per wave ----
    for (int rr = 0; rr < 4; ++rr) {
        const int row = w * 4 + rr;
        const int n = m0 + row;
        const int* sl = slots + (size_t)n * CAP;
        int deg = cnt[n];
        deg = deg > CAP ? CAP : deg;

        float4 acc = make_float4(0.0f, 0.0f, 0.0f, 0.0f);
        int sD0, sD1, sD2, sD3, sD4, sD5, sD6, sD7;
        int iD0, iD1, iD2, iD3, iD4, iD5, iD6, iD7;

        int j = 0;
        int dscN = 0;
        if (deg >= 8) dscN = sl[l & 7];

        while (j + 8 <= deg) {
            GDESC8(dscN)
            if (j + 16 <= deg) dscN = sl[j + 8 + (l & 7)];   // next batch descriptors
            GLOAD1(0) GLOAD1(1) GLOAD1(2) GLOAD1(3)
            GLOAD1(4) GLOAD1(5) GLOAD1(6) GLOAD1(7)
            GFMA1(0) GFMA1(1) GFMA1(2) GFMA1(3)
            GFMA1(4) GFMA1(5) GFMA1(6) GFMA1(7)
            j += 8;
        }

        if (j + 4 <= deg) {
            int d4 = sl[j + (l & 3)];
            GDESC4(d4)
            GLOAD1(0) GLOAD1(1) GLOAD1(2) GLOAD1(3)
            GFMA1(0) GFMA1(1) GFMA1(2) GFMA1(3)
            j += 4;
        }

        // serial tail (<= 3 edges): loads first, then FMAs
        {
            int rem = deg - j;
            if (rem > 0) {
                int sv0 = sl[j];
                sD0 = sv0 & 32767; iD0 = sv0 >> 15;
                GLOAD1(0)
                if (rem > 1) {
                    int sv1 = sl[j + 1];
                    sD1 = sv1 & 32767; iD1 = sv1 >> 15;
                    GLOAD1(1)
                    if (rem > 2) {
                        int sv2 = sl[j + 2];
                        sD2 = sv2 & 32767; iD2 = sv2 >> 15;
                        GLOAD1(2)
                        GFMA1(2)
                    }
                    GFMA1(1)
                }
                GFMA1(0)
            }
        }

        ushort4 st;
        st.x = f2bf(acc.x); st.y = f2bf(acc.y); st.z = f2bf(acc.z); st.w = f2bf(acc.w);
        *(ushort4*)&s_a[row * RS + c4] = st;
    }
    __syncthreads();

    // ---- phase 2: node MLP on the 16 staged rows ----
    const int lr = l & 15, lg = l >> 4, nb = w * 64;
    f32x4 acc2[4];
    #pragma unroll
    for (int nt = 0; nt < 4; ++nt) acc2[nt] = (f32x4)0.0f;

    #pragma unroll 2
    for (int kt = 0; kt < 8; ++kt) {
        bf16x8 a = *(const bf16x8*)&s_a[lr * RS + kt * 32 + lg * 8];
        #pragma unroll
        for (int nt = 0; nt < 4; ++nt) {
            bf16x8 b = *(const bf16x8*)&w4p[(size_t)(((kt * 4 + lg) * 256) + nb + nt * 16 + lr) * 8];
            acc2[nt] = __builtin_amdgcn_mfma_f32_16x16x32_bf16(a, b, acc2[nt], 0, 0, 0);
        }
    }
    __syncthreads();

    #pragma unroll
    for (int nt = 0; nt < 4; ++nt) {
        int col = nb + nt * 16 + lr;
        float bias = b4[col];
        #pragma unroll
        for (int rr = 0; rr < 4; ++rr)
            s_a[(lg * 4 + rr) * RS + col] = f2bf(ssp_f(acc2[nt][rr] + bias));
    }
    __syncthreads();

    #pragma unroll
    for (int nt = 0; nt < 4; ++nt) acc2[nt] = (f32x4)0.0f;

    #pragma unroll 2
    for (int kt = 0; kt < 8; ++kt) {
        bf16x8 a = *(const bf16x8*)&s_a[lr * RS + kt * 32 + lg * 8];
        #pragma unroll
        for (int nt = 0; nt < 4; ++nt) {
            bf16x8 b = *(const bf16x8*)&w5p[(size_t)(((kt * 4 + lg) * 256) + nb + nt * 16 + lr) * 8];
            acc2[nt] = __builtin_amdgcn_mfma_f32_16x16x32_bf16(a, b, acc2[nt], 0, 0, 0);
        }
    }

    #pragma unroll
    for (int nt = 0; nt < 4; ++nt) {
        int col = nb + nt * 16 + lr;
        float bias = b5[col];
        #pragma unroll
        for (int rr = 0; rr < 4; ++rr) {
            int row = m0 + lg * 4 + rr;
            out[(size_t)row * CDIM + col] =
                acc2[nt][rr] + bias + x[(size_t)row * CDIM + col];
        }
    }
}

extern "C" void kernel_launch(void* const* d_in, const int* in_sizes, int n_in,
                              void* d_out, int out_size, void* d_ws, size_t ws_size,
                              hipStream_t stream) {
    const float* pos = (const float*)d_in[0];
    const float* x   = (const float*)d_in[1];
    const int*   snd = (const int*)d_in[2];
    const int*   rcv = (const int*)d_in[3];
    const float* w1  = (const float*)d_in[4];
    const float* b1  = (const float*)d_in[5];
    const float* w2  = (const float*)d_in[6];
    const float* b2  = (const float*)d_in[7];
    const float* w3  = (const float*)d_in[8];
    const float* w4  = (const float*)d_in[9];
    const float* b4  = (const float*)d_in[10];
    const float* w5  = (const float*)d_in[11];
    const float* b5  = (const float*)d_in[12];

    float* out  = (float*)d_out;

    // ws: xw3h bf16 | Wtb bf16 4160x256 | w3p/w4p/w5p | w1p | w2p | cnt | slots(int)
    unsigned char* ws = (unsigned char*)d_ws;
    unsigned short* xw3h = (unsigned short*)ws;
    size_t off = (size_t)NNODES * CDIM * 2;
    unsigned short* Wtb = (unsigned short*)(ws + off); off += (size_t)TROWS * CDIM * 2;
    unsigned short* w3p = (unsigned short*)(ws + off); off += 65536 * 2;
    unsigned short* w4p = (unsigned short*)(ws + off); off += 65536 * 2;
    unsigned short* w5p = (unsigned short*)(ws + off); off += 65536 * 2;
    unsigned short* w1p = (unsigned short*)(ws + off); off += 57344 * 2;
    unsigned short* w2p = (unsigned short*)(ws + off); off += 65536 * 2;
    int* cnt = (int*)(ws + off);                       off += (size_t)NNODES * 4;
    int* slots = (int*)(ws + off);

    packzero_kernel<<<PACKB + ZEROB, NTHR, 0, stream>>>(w3, w4, w5, w1, w2,
                                                        w3p, w4p, w5p, w1p, w2p,
                                                        (int4*)cnt);
    mega_kernel<<<TBLK2 + XW3B2 + FILLB4, NTHR, 0, stream>>>(w1p, b1, w2p, b2, Wtb,
                                                             x, w3p, xw3h,
                                                             pos, snd, rcv, cnt, slots);
    gathernode_kernel<<<GNB, NTHR, 0, stream>>>(cnt, slots, Wtb, xw3h,
                                                w4p, b4, w5p, b5, x, out);
}